// Round 7
// baseline (426.831 us; speedup 1.0000x reference)
//
#include <hip/hip_runtime.h>

// ResidualNetwork forward, fp32, MI355X (gfx950).
// Round 7: v_pk_fma_f32 with the weight pair consumed DIRECTLY as a 64-bit
// scalar operand (aligned SGPR pair) via inline asm "s"(double) — zero VALU
// materialization per weight. Weights prepacked as duplicated (w,w) float2 in
// exact use order (same stream as r3/r6, absmax 0.0). sched_barrier(0) after
// each k-row caps scalar-load hoisting (~10 SGPRs live) — r5's spill fix.
// P=2 points/thread: VGPR ~45 -> 8 resident waves/SIMD hide s_load waits.
// Model: busy/wave = 12,960 pk(4cyc) + 920 relu + ~1.2k misc = 15.1k cyc;
// x32 wave-slots/SIMD = 483k cyc -> ~205-225us (issue floor 173us).
// r4 lesson: no LDS weight delivery (per-CU DS pipe saturates).
// r6 lesson: VGPR allocator serializes pair-interleave; don't rely on it.

#define NPTS 4194304
#define H 10
#define L 10

#define L1_OFF 40
#define BLK_OFF 150
#define BLK_STRIDE 320
#define L8_OFF 3350
#define L9_OFF 3460
#define NENT 3471

typedef float v2f __attribute__((ext_vector_type(2)));

__device__ __forceinline__ v2f bc(float s) { v2f r; r.x = s; r.y = s; return r; }
__device__ __forceinline__ v2f relu2(v2f a) {
    return __builtin_elementwise_max(a, bc(0.0f));
}
// acc = w*h + acc ; w pinned to an SGPR pair (scalar pipe), h/acc VGPR pairs.
__device__ __forceinline__ void pk_fma_s(v2f& acc, double w, v2f h) {
    asm("v_pk_fma_f32 %0, %1, %2, %0" : "+v"(acc) : "s"(w), "v"(h));
}
__device__ __forceinline__ v2f dup2(double d) {
    return __builtin_bit_cast(v2f, d);
}

// ---------------- prepack: weights -> use-order duplicated (w,w) pairs -------
__global__ __launch_bounds__(256) void prepack(
    const float* __restrict__ w0, const float* __restrict__ b0,
    const float* __restrict__ w1, const float* __restrict__ b1,
    const float* __restrict__ Wr1, const float* __restrict__ Br1,
    const float* __restrict__ Wr2, const float* __restrict__ Br2,
    const float* __restrict__ Wr3, const float* __restrict__ Br3,
    const float* __restrict__ w8, const float* __restrict__ b8,
    const float* __restrict__ w9, const float* __restrict__ b9,
    float2* __restrict__ wp)
{
    for (int idx = threadIdx.x; idx < NENT; idx += 256) {
        float v;
        if (idx < L1_OFF) {                       // layer0 per j: b, w0[0][j], w0[1][j], w0[2][j]
            int j = idx >> 2, r = idx & 3;
            v = (r == 0) ? b0[j] : w0[(r - 1) * H + j];
        } else if (idx < BLK_OFF) {               // layer1: b1[10], w1[100]
            int e = idx - L1_OFF;
            v = (e < H) ? b1[e] : w1[e - H];
        } else if (idx < L8_OFF) {                // blocks: B1, W1, B2+B3, W2, W3
            int e = idx - BLK_OFF;
            int l = e / BLK_STRIDE, m = e % BLK_STRIDE;
            if      (m < 10)  v = Br1[l * H + m];
            else if (m < 110) v = Wr1[l * H * H + (m - 10)];
            else if (m < 120) v = Br2[l * H + (m - 110)] + Br3[l * H + (m - 110)];
            else if (m < 220) v = Wr2[l * H * H + (m - 120)];
            else              v = Wr3[l * H * H + (m - 220)];
        } else if (idx < L9_OFF) {                // layer8: b8[10], w8[100]
            int e = idx - L8_OFF;
            v = (e < H) ? b8[e] : w8[e - H];
        } else {                                  // out: b9, w9[10]
            int e = idx - L9_OFF;
            v = (e == 0) ? b9[0] : w9[e - 1];
        }
        float2 d; d.x = v; d.y = v;
        wp[idx] = d;
    }
}

// ---------------- main kernel: 2 points/thread, SGPR-pair pk operands --------
__global__ __launch_bounds__(256, 4) void resnet_fwd(
    const float* __restrict__ x,
    const double* __restrict__ wd,   // the (w,w) stream viewed as 8B scalars
    float* __restrict__ out)
{
    const long i = (long)blockIdx.x * blockDim.x + threadIdx.x;  // pair index
    const float* xp = x + 6 * i;
    v2f X0, X1, X2;
    X0.x = xp[0]; X0.y = xp[3];
    X1.x = xp[1]; X1.y = xp[4];
    X2.x = xp[2]; X2.y = xp[5];

    v2f h[H], t1[H], t2[H];

    // ---- layer 0: 3 -> 10, relu ----
#pragma unroll
    for (int j = 0; j < H; ++j) {
        v2f a = dup2(wd[4 * j]);             // bias pair -> VGPR (mov)
        pk_fma_s(a, wd[4 * j + 1], X0);
        pk_fma_s(a, wd[4 * j + 2], X1);
        pk_fma_s(a, wd[4 * j + 3], X2);
        h[j] = relu2(a);
        __builtin_amdgcn_sched_barrier(0);
    }

    // ---- layer 1: 10 -> 10, relu ----
#pragma unroll
    for (int j = 0; j < H; ++j) t1[j] = dup2(wd[L1_OFF + j]);
#pragma unroll
    for (int k = 0; k < H; ++k) {
#pragma unroll
        for (int j = 0; j < H; ++j)
            pk_fma_s(t1[j], wd[L1_OFF + H + k * H + j], h[k]);
        __builtin_amdgcn_sched_barrier(0);
    }
#pragma unroll
    for (int j = 0; j < H; ++j) h[j] = relu2(t1[j]);

    // ---- L residual blocks ----
#pragma unroll 1
    for (int l = 0; l < L; ++l) {
        const double* __restrict__ wb = wd + BLK_OFF + l * BLK_STRIDE;

        // t1 = relu(h @ W1 + B1)
#pragma unroll
        for (int j = 0; j < H; ++j) t1[j] = dup2(wb[j]);
#pragma unroll
        for (int k = 0; k < H; ++k) {
#pragma unroll
            for (int j = 0; j < H; ++j)
                pk_fma_s(t1[j], wb[10 + k * H + j], h[k]);
            __builtin_amdgcn_sched_barrier(0);
        }
#pragma unroll
        for (int j = 0; j < H; ++j) t1[j] = relu2(t1[j]);

        // t2 = (B2+B3) + h @ W2   (h dies after this)
#pragma unroll
        for (int j = 0; j < H; ++j) t2[j] = dup2(wb[110 + j]);
#pragma unroll
        for (int k = 0; k < H; ++k) {
#pragma unroll
            for (int j = 0; j < H; ++j)
                pk_fma_s(t2[j], wb[120 + k * H + j], h[k]);
            __builtin_amdgcn_sched_barrier(0);
        }

        // t2 += t1 @ W3 ; h = relu(t2)
#pragma unroll
        for (int k = 0; k < H; ++k) {
#pragma unroll
            for (int j = 0; j < H; ++j)
                pk_fma_s(t2[j], wb[220 + k * H + j], t1[k]);
            __builtin_amdgcn_sched_barrier(0);
        }
#pragma unroll
        for (int j = 0; j < H; ++j) h[j] = relu2(t2[j]);
    }

    // ---- layer 8: 10 -> 10, relu ----
#pragma unroll
    for (int j = 0; j < H; ++j) t1[j] = dup2(wd[L8_OFF + j]);
#pragma unroll
    for (int k = 0; k < H; ++k) {
#pragma unroll
        for (int j = 0; j < H; ++j)
            pk_fma_s(t1[j], wd[L8_OFF + H + k * H + j], h[k]);
        __builtin_amdgcn_sched_barrier(0);
    }
#pragma unroll
    for (int j = 0; j < H; ++j) h[j] = relu2(t1[j]);

    // ---- output layer: 10 -> 1 ----
    v2f o = dup2(wd[L9_OFF]);
#pragma unroll
    for (int k = 0; k < H; ++k)
        pk_fma_s(o, wd[L9_OFF + 1 + k], h[k]);

    *(v2f*)(out + 2 * i) = o;
}

extern "C" void kernel_launch(void* const* d_in, const int* in_sizes, int n_in,
                              void* d_out, int out_size, void* d_ws, size_t ws_size,
                              hipStream_t stream)
{
    const float* x   = (const float*)d_in[0];
    const float* w0  = (const float*)d_in[1];
    const float* b0  = (const float*)d_in[2];
    const float* w1  = (const float*)d_in[3];
    const float* b1  = (const float*)d_in[4];
    const float* Wr1 = (const float*)d_in[5];
    const float* Br1 = (const float*)d_in[6];
    const float* Wr2 = (const float*)d_in[7];
    const float* Br2 = (const float*)d_in[8];
    const float* Wr3 = (const float*)d_in[9];
    const float* Br3 = (const float*)d_in[10];
    const float* w8  = (const float*)d_in[11];
    const float* b8  = (const float*)d_in[12];
    const float* w9  = (const float*)d_in[13];
    const float* b9  = (const float*)d_in[14];
    float* out = (float*)d_out;
    float2* wp = (float2*)d_ws;   // 3471 * 8 B = 27.8 KB scratch

    hipLaunchKernelGGL(prepack, dim3(1), dim3(256), 0, stream,
                       w0, b0, w1, b1, Wr1, Br1, Wr2, Br2, Wr3, Br3,
                       w8, b8, w9, b9, wp);

    dim3 block(256);
    dim3 grid(NPTS / 2 / 256);   // 2 points per thread
    hipLaunchKernelGGL(resnet_fwd, grid, block, 0, stream,
                       x, (const double*)wp, out);
}